// Round 1
// baseline (417.047 us; speedup 1.0000x reference)
//
#include <hip/hip_runtime.h>
#include <math.h>

#define N 8192
#define D 64
#define INVT 20.0f
#define EPS 1e-6f
#define TS 128

// ---------------- Kernel 1: norms + diagonal logit ----------------
// one wave (64 lanes) per row; lane l holds element l of the D=64 row.
__global__ __launch_bounds__(256) void norms_kernel(
    const float* __restrict__ A, const float* __restrict__ P,
    float* __restrict__ inv_na, float* __restrict__ inv_np,
    float* __restrict__ diag20) {
    int lane = threadIdx.x & 63;
    int wave = threadIdx.x >> 6;
    int row  = blockIdx.x * 4 + wave;
    float a = A[row * D + lane];
    float p = P[row * D + lane];
    float sa = a * a, sp = p * p, dp = a * p;
    #pragma unroll
    for (int off = 32; off > 0; off >>= 1) {
        sa += __shfl_down(sa, off, 64);
        sp += __shfl_down(sp, off, 64);
        dp += __shfl_down(dp, off, 64);
    }
    if (lane == 0) {
        float na  = sqrtf(sa);
        float npn = sqrtf(sp);
        inv_na[row] = 1.0f / na;
        inv_np[row] = 1.0f / npn;
        diag20[row] = (dp / fmaxf(na * npn, EPS)) * INVT;
    }
}

// ---------------- Kernel 2: tiled sim + exp + row/col sums ----------------
// grid = (64, 64, 3); z: 0=A*P^T (rows+cols), 1=A*A^T (rows, skip diag),
//                        2=P*P^T (cols, skip diag). All accumulate into part[].
// LDS: two 64x128 fp32 tiles, transposed [k][r], XOR-swizzled:
//   pos(r,k) = r ^ (((k>>2)&3)<<3)  -> conflict-free b64 fragment reads.
__global__ __launch_bounds__(256, 2) void tiles_kernel(
    const float* __restrict__ A, const float* __restrict__ P,
    const float* __restrict__ inv_na, const float* __restrict__ inv_np,
    float* __restrict__ part) {
    __shared__ float sm[2 * 64 * 128];   // 64 KB
    float* Xt = sm;
    float* Yt = sm + 64 * 128;

    const int mode = blockIdx.z;
    const float *X, *Y, *ivx, *ivy;
    bool do_rows, do_cols, skip_diag;
    if (mode == 0)      { X = A; Y = P; ivx = inv_na; ivy = inv_np; do_rows = true;  do_cols = true;  skip_diag = false; }
    else if (mode == 1) { X = A; Y = A; ivx = inv_na; ivy = inv_na; do_rows = true;  do_cols = false; skip_diag = true;  }
    else                { X = P; Y = P; ivx = inv_np; ivy = inv_np; do_rows = false; do_cols = true;  skip_diag = true;  }

    const int bi = blockIdx.y, bj = blockIdx.x;
    const int tid = threadIdx.x;
    const int lr = tid >> 4;     // 0..15
    const int lk = tid & 15;     // float4 index along D
    const int fw = (lk & 3) << 3;  // write-side xor ( ((k>>2)&3)<<3 with k=4*lk+c )

    // stage both tiles, transposed into [k][r^swz]
    #pragma unroll
    for (int it = 0; it < 8; ++it) {
        int r = lr + (it << 4);
        float4 v = *(const float4*)(X + (bi * TS + r) * D + (lk << 2));
        float4 w = *(const float4*)(Y + (bj * TS + r) * D + (lk << 2));
        int k0 = lk << 2;
        int rs = r ^ fw;
        Xt[((k0 + 0) << 7) + rs] = v.x;
        Xt[((k0 + 1) << 7) + rs] = v.y;
        Xt[((k0 + 2) << 7) + rs] = v.z;
        Xt[((k0 + 3) << 7) + rs] = v.w;
        Yt[((k0 + 0) << 7) + rs] = w.x;
        Yt[((k0 + 1) << 7) + rs] = w.y;
        Yt[((k0 + 2) << 7) + rs] = w.z;
        Yt[((k0 + 3) << 7) + rs] = w.w;
    }
    __syncthreads();

    const int tx = tid & 15, ty = tid >> 4;
    const int tx2 = tx << 1, ty2 = ty << 1;

    float acc[8][8];
    #pragma unroll
    for (int i = 0; i < 8; ++i)
        #pragma unroll
        for (int j = 0; j < 8; ++j) acc[i][j] = 0.0f;

    #pragma unroll 4
    for (int k = 0; k < D; ++k) {
        const int f  = ((k >> 2) & 3) << 3;
        const int kb = k << 7;
        float af[8], bf[8];
        #pragma unroll
        for (int rr = 0; rr < 4; ++rr) {
            float2 t = *(const float2*)&Xt[kb + ((ty2 + (rr << 5)) ^ f)];
            af[2 * rr] = t.x; af[2 * rr + 1] = t.y;
        }
        #pragma unroll
        for (int cc = 0; cc < 4; ++cc) {
            float2 t = *(const float2*)&Yt[kb + ((tx2 + (cc << 5)) ^ f)];
            bf[2 * cc] = t.x; bf[2 * cc + 1] = t.y;
        }
        #pragma unroll
        for (int i = 0; i < 8; ++i)
            #pragma unroll
            for (int j = 0; j < 8; ++j)
                acc[i][j] = fmaf(af[i], bf[j], acc[i][j]);
    }

    // epilogue: scale -> exp -> per-thread row/col partials
    int grow[8], gcol[8];
    float ivr[8], ivc[8];
    #pragma unroll
    for (int i = 0; i < 8; ++i) {
        int rl = ty2 + ((i >> 1) << 5) + (i & 1);
        int cl = tx2 + ((i >> 1) << 5) + (i & 1);
        grow[i] = bi * TS + rl;
        gcol[i] = bj * TS + cl;
        ivr[i] = ivx[grow[i]];
        ivc[i] = ivy[gcol[i]];
    }
    float rsum[8], csum[8];
    #pragma unroll
    for (int i = 0; i < 8; ++i) { rsum[i] = 0.0f; csum[i] = 0.0f; }
    #pragma unroll
    for (int i = 0; i < 8; ++i)
        #pragma unroll
        for (int j = 0; j < 8; ++j) {
            float e = __expf(acc[i][j] * ivr[i] * ivc[j] * INVT);
            if (skip_diag && grow[i] == gcol[j]) e = 0.0f;
            rsum[i] += e; csum[j] += e;
        }

    // block reduce via LDS (reuse tile memory), then global atomics
    float (*red)[8] = (float(*)[8])sm;
    if (do_rows) {
        __syncthreads();
        #pragma unroll
        for (int i = 0; i < 8; ++i) red[tid][i] = rsum[i];
        __syncthreads();
        if (tid < 128) {
            int tyr = tid >> 3, ri = tid & 7;
            float s = 0.0f;
            #pragma unroll
            for (int m = 0; m < 16; ++m) s += red[tyr * 16 + m][ri];
            int row = bi * TS + (tyr << 1) + ((ri >> 1) << 5) + (ri & 1);
            atomicAdd(part + row, s);
        }
    }
    if (do_cols) {
        __syncthreads();
        #pragma unroll
        for (int j = 0; j < 8; ++j) red[tid][j] = csum[j];
        __syncthreads();
        if (tid < 128) {
            int txr = tid >> 3, ci = tid & 7;
            float s = 0.0f;
            #pragma unroll
            for (int m = 0; m < 16; ++m) s += red[m * 16 + txr][ci];
            int col = bj * TS + (txr << 1) + ((ci >> 1) << 5) + (ci & 1);
            atomicAdd(part + col, s);
        }
    }
}

// ---------------- Kernel 3: per-row loss contribution + reduce ----------------
__global__ __launch_bounds__(256) void loss_kernel(
    const float* __restrict__ part, const float* __restrict__ diag20,
    float* __restrict__ acc) {
    int i = blockIdx.x * 256 + threadIdx.x;
    float v = logf(part[i]) - diag20[i];
    #pragma unroll
    for (int off = 32; off > 0; off >>= 1) v += __shfl_down(v, off, 64);
    __shared__ float ws[4];
    int lane = threadIdx.x & 63, wv = threadIdx.x >> 6;
    if (lane == 0) ws[wv] = v;
    __syncthreads();
    if (threadIdx.x == 0) atomicAdd(acc, ws[0] + ws[1] + ws[2] + ws[3]);
}

__global__ void finalize_kernel(const float* __restrict__ acc, float* __restrict__ out) {
    out[0] = acc[0] * (1.0f / (float)N);
}

// ---------------- launch ----------------
extern "C" void kernel_launch(void* const* d_in, const int* in_sizes, int n_in,
                              void* d_out, int out_size, void* d_ws, size_t ws_size,
                              hipStream_t stream) {
    const float* A = (const float*)d_in[0];
    const float* P = (const float*)d_in[1];
    float* ws      = (float*)d_ws;
    float* inv_na  = ws;
    float* inv_np  = ws + N;
    float* diag20  = ws + 2 * N;
    float* part    = ws + 3 * N;
    float* lacc    = ws + 4 * N;

    // part[] and loss accumulator must start at zero (ws is poisoned)
    hipMemsetAsync(part, 0, (N + 1) * sizeof(float), stream);

    norms_kernel<<<N / 4, 256, 0, stream>>>(A, P, inv_na, inv_np, diag20);

    dim3 grid(N / TS, N / TS, 3);
    tiles_kernel<<<grid, 256, 0, stream>>>(A, P, inv_na, inv_np, part);

    loss_kernel<<<N / 256, 256, 0, stream>>>(part, diag20, lacc);
    finalize_kernel<<<1, 1, 0, stream>>>(lacc, (float*)d_out);
}

// Round 2
// 135.921 us; speedup vs baseline: 3.0683x; 3.0683x over previous
//
#include <hip/hip_runtime.h>
#include <hip/hip_bf16.h>
#include <math.h>

#define N 8192
#define D 64
#define INVT 20.0f
#define EPS 1e-6f

typedef __attribute__((ext_vector_type(8))) short bf16x8;
typedef __attribute__((ext_vector_type(4))) float f32x4;

// ---------------- Kernel 1: normalize -> bf16 Z, exact diag logit ----------------
// one wave per row pair (a_i, p_i); lane l holds element l (D=64).
__global__ __launch_bounds__(256) void prep_kernel(
    const float* __restrict__ A, const float* __restrict__ P,
    __hip_bfloat16* __restrict__ Zn, float* __restrict__ diag20) {
    int lane = threadIdx.x & 63;
    int wave = threadIdx.x >> 6;
    int row  = blockIdx.x * 4 + wave;
    float a = A[row * D + lane];
    float p = P[row * D + lane];
    float sa = a * a, sp = p * p, dp = a * p;
    #pragma unroll
    for (int off = 1; off < 64; off <<= 1) {
        sa += __shfl_xor(sa, off, 64);
        sp += __shfl_xor(sp, off, 64);
        dp += __shfl_xor(dp, off, 64);
    }
    float na  = sqrtf(sa);
    float npn = sqrtf(sp);
    Zn[row * D + lane]       = __float2bfloat16(a / na);
    Zn[(N + row) * D + lane] = __float2bfloat16(p / npn);
    if (lane == 0)
        diag20[row] = (dp / fmaxf(na * npn, EPS)) * INVT;
}

// ---------------- Kernel 2: upper-triangular Z-gram tiles, MFMA bf16 ----------------
// block = 256 threads = 4 waves; 128x128 output tile; each wave a 64x64 subtile
// of 4x4 mfma_f32_16x16x32_bf16. LDS tiles padded to 72 shorts (144 B = 9 uint4)
// per row -> 16B-aligned, 2-way-max bank aliasing on b128 reads/writes.
__global__ __launch_bounds__(256) void tiles_kernel(
    const __hip_bfloat16* __restrict__ Zn, float* __restrict__ part) {
    __shared__ ushort sm_u[2 * 128 * 72];   // 36 KB

    // unrank blockIdx.x -> (bi, bj), 0 <= bi <= bj < 128
    int t = (int)blockIdx.x;
    int b = (int)((257.0f - sqrtf(66049.0f - 8.0f * (float)t)) * 0.5f);
    while (b * (257 - b) / 2 > t) --b;
    while ((b + 1) * (256 - b) / 2 <= t) ++b;
    const int bi = b;
    const int bj = b + (t - b * (257 - b) / 2);
    const bool diag = (bi == bj);

    const int tid = threadIdx.x;

    // stage X (rows of bi) and Y (rows of bj), coalesced 16B per lane
    const uint4* Zu = (const uint4*)Zn;     // 8 uint4 per 64-bf16 row
    uint4* Xu = (uint4*)sm_u;               // 9 uint4 per padded row
    uint4* Yu = Xu + 128 * 9;
    #pragma unroll
    for (int it = 0; it < 4; ++it) {
        int c   = tid + it * 256;           // 0..1023
        int row = c >> 3, kb = c & 7;
        Xu[row * 9 + kb] = Zu[(bi * 128 + row) * 8 + kb];
        Yu[row * 9 + kb] = Zu[(bj * 128 + row) * 8 + kb];
    }
    __syncthreads();

    const int lane = tid & 63, w = tid >> 6;
    const int wr = w >> 1, wc = w & 1;      // wave subtile (64x64) coords
    const int ln = lane & 15, q = lane >> 4;

    f32x4 acc[4][4] = {};
    const bf16x8* Xf = (const bf16x8*)sm_u; // 16B units: row*9 + kc*4 + q
    const bf16x8* Yf = Xf + 128 * 9;

    #pragma unroll
    for (int kc = 0; kc < 2; ++kc) {
        bf16x8 af[4], bfr[4];
        #pragma unroll
        for (int ii = 0; ii < 4; ++ii)
            af[ii] = Xf[(wr * 64 + ii * 16 + ln) * 9 + kc * 4 + q];
        #pragma unroll
        for (int jj = 0; jj < 4; ++jj)
            bfr[jj] = Yf[(wc * 64 + jj * 16 + ln) * 9 + kc * 4 + q];
        #pragma unroll
        for (int ii = 0; ii < 4; ++ii)
            #pragma unroll
            for (int jj = 0; jj < 4; ++jj)
                acc[ii][jj] = __builtin_amdgcn_mfma_f32_16x16x32_bf16(
                    af[ii], bfr[jj], acc[ii][jj], 0, 0, 0);
    }

    // epilogue: exp(20*cos), diag skip, per-lane row/col partials
    float rsum[16], csum[4];
    #pragma unroll
    for (int m = 0; m < 16; ++m) rsum[m] = 0.0f;
    #pragma unroll
    for (int j = 0; j < 4; ++j) csum[j] = 0.0f;

    #pragma unroll
    for (int ii = 0; ii < 4; ++ii)
        #pragma unroll
        for (int jj = 0; jj < 4; ++jj)
            #pragma unroll
            for (int r = 0; r < 4; ++r) {
                float e = __expf(acc[ii][jj][r] * INVT);
                if (diag && (wr * 64 + ii * 16 + q * 4 + r) ==
                            (wc * 64 + jj * 16 + ln))
                    e = 0.0f;
                rsum[ii * 4 + r] += e;
                csum[jj] += e;
            }

    // reduce rows across the 16 lanes sharing a row (vary ln), cols across quads
    #pragma unroll
    for (int m = 0; m < 16; ++m) {
        float v = rsum[m];
        v += __shfl_xor(v, 1, 64);
        v += __shfl_xor(v, 2, 64);
        v += __shfl_xor(v, 4, 64);
        v += __shfl_xor(v, 8, 64);
        rsum[m] = v;
    }
    #pragma unroll
    for (int j = 0; j < 4; ++j) {
        float v = csum[j];
        v += __shfl_xor(v, 16, 64);
        v += __shfl_xor(v, 32, 64);
        csum[j] = v;
    }

    __syncthreads();   // done with tiles; reuse LDS for block reduce
    float* rb = (float*)sm_u;        // [2][128] row partials
    float* cb = rb + 256;            // [2][128] col partials
    if (ln == 0) {                   // 4 lanes/wave (q = 0..3)
        #pragma unroll
        for (int ii = 0; ii < 4; ++ii)
            #pragma unroll
            for (int r = 0; r < 4; ++r)
                rb[(w & 1) * 128 + wr * 64 + ii * 16 + q * 4 + r] = rsum[ii * 4 + r];
    }
    if (q == 0) {                    // 16 lanes/wave
        #pragma unroll
        for (int jj = 0; jj < 4; ++jj)
            cb[wr * 128 + wc * 64 + jj * 16 + ln] = csum[jj];
    }
    __syncthreads();

    if (tid < 128) {
        atomicAdd(part + bi * 128 + tid, rb[tid] + rb[128 + tid]);
    } else if (!diag) {
        int col = tid - 128;
        atomicAdd(part + bj * 128 + col, cb[col] + cb[128 + col]);
    }
}

// ---------------- Kernel 3: per-row loss + reduce ----------------
__global__ __launch_bounds__(256) void loss_kernel(
    const float* __restrict__ part, const float* __restrict__ diag20,
    float* __restrict__ acc) {
    int i = blockIdx.x * 256 + threadIdx.x;
    float partition = part[i] + part[N + i];
    float v = logf(partition) - diag20[i];
    #pragma unroll
    for (int off = 32; off > 0; off >>= 1) v += __shfl_down(v, off, 64);
    __shared__ float wsm[4];
    int lane = threadIdx.x & 63, wv = threadIdx.x >> 6;
    if (lane == 0) wsm[wv] = v;
    __syncthreads();
    if (threadIdx.x == 0) atomicAdd(acc, wsm[0] + wsm[1] + wsm[2] + wsm[3]);
}

__global__ void finalize_kernel(const float* __restrict__ acc, float* __restrict__ out) {
    out[0] = acc[0] * (1.0f / (float)N);
}

// ---------------- launch ----------------
extern "C" void kernel_launch(void* const* d_in, const int* in_sizes, int n_in,
                              void* d_out, int out_size, void* d_ws, size_t ws_size,
                              hipStream_t stream) {
    const float* A = (const float*)d_in[0];
    const float* P = (const float*)d_in[1];

    __hip_bfloat16* Zn = (__hip_bfloat16*)d_ws;                    // 2N*64 bf16 = 2 MiB
    float* part   = (float*)((char*)d_ws + 2u * N * D * sizeof(__hip_bfloat16));
    float* lacc   = part + 2 * N;
    float* diag20 = lacc + 1;

    // zero part[2N] + lacc (ws is poisoned each call)
    hipMemsetAsync(part, 0, (2 * N + 1) * sizeof(float), stream);

    prep_kernel<<<N / 4, 256, 0, stream>>>(A, P, Zn, diag20);

    const int nblocks = 128 * 129 / 2;   // 8256 upper-triangular 128-tiles
    tiles_kernel<<<nblocks, 256, 0, stream>>>(Zn, part);

    loss_kernel<<<N / 256, 256, 0, stream>>>(part, diag20, lacc);
    finalize_kernel<<<1, 1, 0, stream>>>(lacc, (float*)d_out);
}

// Round 3
// 131.557 us; speedup vs baseline: 3.1701x; 1.0332x over previous
//
#include <hip/hip_runtime.h>
#include <hip/hip_bf16.h>
#include <math.h>

#define N 8192
#define D 64
#define INVT 20.0f
#define EPS 1e-6f
// sqrt(20/ln2): gram(Z) = 20*log2(e)*cos, so exp2(gram) = e^{20 cos}
#define ZSCALE 5.3715835f

typedef __attribute__((ext_vector_type(8))) short bf16x8;
typedef __attribute__((ext_vector_type(4))) float f32x4;

#if __has_builtin(__builtin_amdgcn_exp2f)
#define EXP2F(x) __builtin_amdgcn_exp2f(x)
#else
#define EXP2F(x) exp2f(x)
#endif

// ---------------- Kernel 1: normalize -> scaled bf16 Z, exact diag logit,
//                  and zero part[]/lacc/cnt (replaces memset) ----------------
__global__ __launch_bounds__(256) void prep_kernel(
    const float* __restrict__ A, const float* __restrict__ P,
    __hip_bfloat16* __restrict__ Zn, float* __restrict__ diag20,
    float* __restrict__ part, float* __restrict__ lacc, unsigned* __restrict__ cnt) {
    // zero the 2N part accumulators + loss accumulator + ticket counter
    if (blockIdx.x < 64) part[blockIdx.x * 256 + threadIdx.x] = 0.0f;
    else if (blockIdx.x == 64 && threadIdx.x == 0) { *lacc = 0.0f; *cnt = 0u; }

    int lane = threadIdx.x & 63;
    int wave = threadIdx.x >> 6;
    int row  = blockIdx.x * 4 + wave;
    float a = A[row * D + lane];
    float p = P[row * D + lane];
    float sa = a * a, sp = p * p, dp = a * p;
    #pragma unroll
    for (int off = 1; off < 64; off <<= 1) {
        sa += __shfl_xor(sa, off, 64);
        sp += __shfl_xor(sp, off, 64);
        dp += __shfl_xor(dp, off, 64);
    }
    float na  = sqrtf(sa);
    float npn = sqrtf(sp);
    Zn[row * D + lane]       = __float2bfloat16(a * (ZSCALE / na));
    Zn[(N + row) * D + lane] = __float2bfloat16(p * (ZSCALE / npn));
    if (lane == 0)
        diag20[row] = (dp / fmaxf(na * npn, EPS)) * INVT;
}

// ---------------- Kernel 2: upper-triangular Z-gram, MFMA from global ----------------
// 128x128 tile / block (4 waves, each a 64x64 subtile of 4x4 mfma_16x16x32_bf16).
// No LDS staging: fragments are coalesced b128 loads straight from L2-resident Z.
// LDS only for the wave-local row-sum transpose (no barriers in the whole kernel).
__global__ __launch_bounds__(256) void tiles_kernel(
    const __hip_bfloat16* __restrict__ Zn, float* __restrict__ part) {
    __shared__ float rs[4][16][68];   // 17408 B; padded: 68 % 32 banks -> 2-way max

    // unrank blockIdx.x -> (bi, bj), 0 <= bi <= bj < 128
    int t = (int)blockIdx.x;
    int b = (int)((257.0f - sqrtf(66049.0f - 8.0f * (float)t)) * 0.5f);
    while (b * (257 - b) / 2 > t) --b;
    while ((b + 1) * (256 - b) / 2 <= t) ++b;
    const int bi = b;
    const int bj = b + (t - b * (257 - b) / 2);

    const int tid  = threadIdx.x;
    const int lane = tid & 63, w = tid >> 6;
    const int wr = w >> 1, wc = w & 1;      // wave's 64x64 subtile coords
    const int ln = lane & 15, q = lane >> 4;

    // fragment base indices in 16B units (8 units per 64-elem row)
    const bf16x8* Zf = (const bf16x8*)Zn;
    const int abase = (bi * 128 + wr * 64 + ln) * 8 + q;
    const int bbase = (bj * 128 + wc * 64 + ln) * 8 + q;

    f32x4 acc[4][4] = {};
    #pragma unroll
    for (int kc = 0; kc < 2; ++kc) {
        bf16x8 af[4], bv[4];
        #pragma unroll
        for (int ii = 0; ii < 4; ++ii) af[ii] = Zf[abase + ii * 128 + kc * 4];
        #pragma unroll
        for (int jj = 0; jj < 4; ++jj) bv[jj] = Zf[bbase + jj * 128 + kc * 4];
        #pragma unroll
        for (int ii = 0; ii < 4; ++ii)
            #pragma unroll
            for (int jj = 0; jj < 4; ++jj)
                acc[ii][jj] = __builtin_amdgcn_mfma_f32_16x16x32_bf16(
                    af[ii], bv[jj], acc[ii][jj], 0, 0, 0);
    }

    // epilogue: e = exp2(gram) = e^{20 cos}; diag elements zeroed (== ref's -e^{1/T})
    const bool dwave = (bi == bj) && (wr == wc);
    f32x4 rsumv[4] = {};
    f32x4 csumv[4] = {};
    #pragma unroll
    for (int ii = 0; ii < 4; ++ii)
        #pragma unroll
        for (int jj = 0; jj < 4; ++jj) {
            f32x4 e;
            #pragma unroll
            for (int r = 0; r < 4; ++r) e[r] = EXP2F(acc[ii][jj][r]);
            if (dwave && (ii == jj)) {
                #pragma unroll
                for (int r = 0; r < 4; ++r)
                    if (ln == q * 4 + r) e[r] = 0.0f;
            }
            rsumv[ii] += e;   // accumulate over jj (per-row partials, this lane's cols)
            csumv[jj] += e;   // accumulate over ii (per-col partials, r-component-wise)
        }

    // row sums: wave-local LDS transpose (no barrier), then 1 coalesced atomic/lane.
    // write: lane (q,ln) -> rs[w][ln][ii*16 + q*4 .. +3]  (b128, 2-way banks)
    #pragma unroll
    for (int ii = 0; ii < 4; ++ii)
        *(f32x4*)&rs[w][ln][ii * 16 + q * 4] = rsumv[ii];
    float rowsum = 0.0f;
    #pragma unroll
    for (int l = 0; l < 16; ++l) rowsum += rs[w][l][lane];  // stride-1 across lanes
    atomicAdd(part + bi * 128 + wr * 64 + lane, rowsum);

    // col sums: horizontal 4->1 then 2-step butterfly over q; 1 atomic/lane
    float cs0, cs1, cs2, cs3;
    {
        f32x4 v0 = csumv[0], v1 = csumv[1], v2 = csumv[2], v3 = csumv[3];
        cs0 = (v0[0] + v0[1]) + (v0[2] + v0[3]);
        cs1 = (v1[0] + v1[1]) + (v1[2] + v1[3]);
        cs2 = (v2[0] + v2[1]) + (v2[2] + v2[3]);
        cs3 = (v3[0] + v3[1]) + (v3[2] + v3[3]);
        cs0 += __shfl_xor(cs0, 16, 64); cs0 += __shfl_xor(cs0, 32, 64);
        cs1 += __shfl_xor(cs1, 16, 64); cs1 += __shfl_xor(cs1, 32, 64);
        cs2 += __shfl_xor(cs2, 16, 64); cs2 += __shfl_xor(cs2, 32, 64);
        cs3 += __shfl_xor(cs3, 16, 64); cs3 += __shfl_xor(cs3, 32, 64);
    }
    if (bi != bj) {
        float cval = (q == 0) ? cs0 : (q == 1) ? cs1 : (q == 2) ? cs2 : cs3;
        atomicAdd(part + bj * 128 + wc * 64 + q * 16 + ln, cval);
    }
}

// ---------------- Kernel 3: per-row loss + reduce + last-block finalize ----------------
__global__ __launch_bounds__(256) void loss_kernel(
    const float* __restrict__ part, const float* __restrict__ diag20,
    float* __restrict__ lacc, unsigned* __restrict__ cnt, float* __restrict__ out) {
    int i = blockIdx.x * 256 + threadIdx.x;
    float v = logf(part[i] + part[N + i]) - diag20[i];
    #pragma unroll
    for (int off = 32; off > 0; off >>= 1) v += __shfl_down(v, off, 64);
    __shared__ float wsm[4];
    int lane = threadIdx.x & 63, wv = threadIdx.x >> 6;
    if (lane == 0) wsm[wv] = v;
    __syncthreads();
    if (threadIdx.x == 0) {
        atomicAdd(lacc, wsm[0] + wsm[1] + wsm[2] + wsm[3]);
        __threadfence();
        unsigned old = atomicAdd(cnt, 1u);
        if (old == (N / 256 - 1)) {
            float tot = atomicAdd(lacc, 0.0f);   // read full sum
            out[0] = tot * (1.0f / (float)N);
        }
    }
}

// ---------------- launch ----------------
extern "C" void kernel_launch(void* const* d_in, const int* in_sizes, int n_in,
                              void* d_out, int out_size, void* d_ws, size_t ws_size,
                              hipStream_t stream) {
    const float* A = (const float*)d_in[0];
    const float* P = (const float*)d_in[1];

    __hip_bfloat16* Zn = (__hip_bfloat16*)d_ws;                 // 2N*64 bf16 = 2 MiB
    float* part   = (float*)((char*)d_ws + 2u * N * D * sizeof(__hip_bfloat16));
    float* diag20 = part + 2 * N;
    float* lacc   = diag20 + N;
    unsigned* cnt = (unsigned*)(lacc + 1);

    prep_kernel<<<N / 4, 256, 0, stream>>>(A, P, Zn, diag20, part, lacc, cnt);

    const int nblocks = 128 * 129 / 2;   // 8256 upper-triangular 128-tiles
    tiles_kernel<<<nblocks, 256, 0, stream>>>(Zn, part);

    loss_kernel<<<N / 256, 256, 0, stream>>>(part, diag20, lacc, cnt, (float*)d_out);
}